// Round 1
// baseline (3707.454 us; speedup 1.0000x reference)
//
#include <hip/hip_runtime.h>
#include <math.h>

#define HDIM 128

// ---------------- generic fp32 GEMM: C[M,NC] = act(A[M,K] @ B[K,NC]) --------
// BM=128, BN=64, BK=32, 256 threads, 8x4 microtile per thread.
template<int ACT> // 0 = none, 1 = tanh
__global__ __launch_bounds__(256) void gemm_k(const float* __restrict__ A,
                                              const float* __restrict__ B,
                                              float* __restrict__ C,
                                              int M, int K, int NC) {
    __shared__ float At[32][132];   // [k][row], 132*4B = 33*16B -> float4-aligned rows
    __shared__ float Bs[32][64];
    const int tid = threadIdx.x;
    const int tx = tid & 15;        // 16 col-groups of 4
    const int ty = tid >> 4;        // 16 row-groups of 8
    const int row0 = blockIdx.x * 128;
    const int col0 = blockIdx.y * 64;

    float acc[8][4];
#pragma unroll
    for (int i = 0; i < 8; ++i)
#pragma unroll
        for (int j = 0; j < 4; ++j) acc[i][j] = 0.f;

    for (int kc = 0; kc < K; kc += 32) {
        // A tile: 128 rows x 32 cols = 1024 float4 -> 4 per thread, store transposed
#pragma unroll
        for (int i = 0; i < 4; ++i) {
            int idx = tid + i * 256;
            int r = idx >> 3, c4 = idx & 7;
            float4 v = make_float4(0.f, 0.f, 0.f, 0.f);
            int gr = row0 + r;
            if (gr < M) v = *reinterpret_cast<const float4*>(&A[(size_t)gr * K + kc + c4 * 4]);
            At[c4 * 4 + 0][r] = v.x; At[c4 * 4 + 1][r] = v.y;
            At[c4 * 4 + 2][r] = v.z; At[c4 * 4 + 3][r] = v.w;
        }
        // B tile: 32 rows x 64 cols = 512 float4 -> 2 per thread
#pragma unroll
        for (int i = 0; i < 2; ++i) {
            int idx = tid + i * 256;
            int r = idx >> 4, c4 = idx & 15;
            float4 v = *reinterpret_cast<const float4*>(&B[(size_t)(kc + r) * NC + col0 + c4 * 4]);
            *reinterpret_cast<float4*>(&Bs[r][c4 * 4]) = v;
        }
        __syncthreads();
#pragma unroll
        for (int k = 0; k < 32; ++k) {
            float a[8], b[4];
            *reinterpret_cast<float4*>(&a[0]) = *reinterpret_cast<const float4*>(&At[k][ty * 8]);
            *reinterpret_cast<float4*>(&a[4]) = *reinterpret_cast<const float4*>(&At[k][ty * 8 + 4]);
            *reinterpret_cast<float4*>(&b[0]) = *reinterpret_cast<const float4*>(&Bs[k][tx * 4]);
#pragma unroll
            for (int i = 0; i < 8; ++i)
#pragma unroll
                for (int j = 0; j < 4; ++j)
                    acc[i][j] = fmaf(a[i], b[j], acc[i][j]);
        }
        __syncthreads();
    }
#pragma unroll
    for (int i = 0; i < 8; ++i) {
        int gr = row0 + ty * 8 + i;
        if (gr < M) {
            float4 v = make_float4(acc[i][0], acc[i][1], acc[i][2], acc[i][3]);
            if (ACT == 1) { v.x = tanhf(v.x); v.y = tanhf(v.y); v.z = tanhf(v.z); v.w = tanhf(v.w); }
            *reinterpret_cast<float4*>(&C[(size_t)gr * NC + col0 + tx * 4]) = v;
        }
    }
}

// ---------------- CSR build -------------------------------------------------
__global__ void zero_int(int* p, int n) {
    int i = blockIdx.x * 256 + threadIdx.x;
    if (i < n) p[i] = 0;
}

__global__ void hist_kernel(const int* __restrict__ dst, int* __restrict__ cnt, int E) {
    int e = blockIdx.x * 256 + threadIdx.x;
    if (e < E) atomicAdd(&cnt[dst[e]], 1);
}

// single-block chunked exclusive scan; cnt_cursor: in=counts, out=start offsets
__global__ __launch_bounds__(1024) void scan_kernel(int* __restrict__ cnt_cursor,
                                                    int* __restrict__ row_off, int n) {
    __shared__ int sm[1024];
    __shared__ int carry_s;
    const int tid = threadIdx.x;
    if (tid == 0) carry_s = 0;
    __syncthreads();
    for (int base = 0; base < n; base += 1024) {
        int i = base + tid;
        int v = (i < n) ? cnt_cursor[i] : 0;
        sm[tid] = v;
        __syncthreads();
        for (int off = 1; off < 1024; off <<= 1) {
            int t = (tid >= off) ? sm[tid - off] : 0;
            __syncthreads();
            sm[tid] += t;
            __syncthreads();
        }
        int excl = sm[tid] - v;
        int carry = carry_s;
        int total = sm[1023];
        if (i < n) { row_off[i] = carry + excl; cnt_cursor[i] = carry + excl; }
        __syncthreads();
        if (tid == 0) carry_s = carry + total;
        __syncthreads();
    }
    if (tid == 0) row_off[n] = carry_s;
}

__global__ void scatter_kernel(const int* __restrict__ src, const int* __restrict__ dst,
                               int* __restrict__ cursor, int* __restrict__ ssrc, int E) {
    int e = blockIdx.x * 256 + threadIdx.x;
    if (e < E) {
        int p = atomicAdd(&cursor[dst[e]], 1);
        ssrc[p] = src[e];
    }
}

// ---------------- edge aggregation: one wave per node -----------------------
__global__ __launch_bounds__(256) void agg_kernel(const float* __restrict__ m,
                                                  const int* __restrict__ row_off,
                                                  const int* __restrict__ ssrc,
                                                  float* __restrict__ agg, int M) {
    int node = (blockIdx.x * 256 + threadIdx.x) >> 6;
    int lane = threadIdx.x & 63;
    if (node >= M) return;
    int lo = row_off[node], hi = row_off[node + 1];
    float2 acc = make_float2(0.f, 0.f);
    for (int i = lo; i < hi; ++i) {
        int s = ssrc[i];
        float2 v = *reinterpret_cast<const float2*>(&m[(size_t)s * HDIM + lane * 2]);
        acc.x += v.x; acc.y += v.y;
    }
    *reinterpret_cast<float2*>(&agg[(size_t)node * HDIM + lane * 2]) = acc;
}

// ---------------- fused GRU: gi/gh strips + gates, never materialized -------
// block: 64 rows x 32 gate-cols (blockIdx.y in 0..3). 256 thr: j=tid&31, ty=tid>>5.
__global__ __launch_bounds__(256) void gru_kernel(const float* __restrict__ agg,
                                                  const float* __restrict__ h,
                                                  const float* __restrict__ WihT,  // [128][384]
                                                  const float* __restrict__ WhhT,  // [128][384]
                                                  const float* __restrict__ bih,
                                                  const float* __restrict__ bhh,
                                                  float* __restrict__ hout, int M) {
    __shared__ float Agt[32][68];     // [k][row], 68*4B = 17*16B
    __shared__ float Ht[32][68];
    __shared__ float Bsm[6][32][32];  // strips: 0..2 WihT(r,z,n), 3..5 WhhT(r,z,n)
    const int tid = threadIdx.x;
    const int j = tid & 31;
    const int ty = tid >> 5;          // 0..7, each owns rows ty*8..ty*8+7
    const int row0 = blockIdx.x * 64;
    const int cb = blockIdx.y;        // col strip of 32 within H

    float acc[6][8];
#pragma unroll
    for (int s = 0; s < 6; ++s)
#pragma unroll
        for (int r = 0; r < 8; ++r) acc[s][r] = 0.f;

    for (int kc = 0; kc < HDIM; kc += 32) {
        // agg & h tiles (64x32), transposed into LDS: 512 float4 each -> 2/thread
#pragma unroll
        for (int i = 0; i < 2; ++i) {
            int idx = tid + i * 256;
            int r = idx >> 3, c4 = idx & 7;
            int gr = row0 + r;
            float4 va = make_float4(0.f, 0.f, 0.f, 0.f), vh = va;
            if (gr < M) {
                va = *reinterpret_cast<const float4*>(&agg[(size_t)gr * HDIM + kc + c4 * 4]);
                vh = *reinterpret_cast<const float4*>(&h[(size_t)gr * HDIM + kc + c4 * 4]);
            }
            Agt[c4 * 4 + 0][r] = va.x; Agt[c4 * 4 + 1][r] = va.y;
            Agt[c4 * 4 + 2][r] = va.z; Agt[c4 * 4 + 3][r] = va.w;
            Ht[c4 * 4 + 0][r] = vh.x; Ht[c4 * 4 + 1][r] = vh.y;
            Ht[c4 * 4 + 2][r] = vh.z; Ht[c4 * 4 + 3][r] = vh.w;
        }
        // 6 B strips, 32k x 32c each: 1536 float4 -> 6/thread
#pragma unroll
        for (int i = 0; i < 6; ++i) {
            int idx = tid + i * 256;
            int s = idx >> 8;
            int rem = idx & 255;
            int r = rem >> 3, c4 = rem & 7;
            const float* W = (s < 3) ? WihT : WhhT;
            int colbase = (s % 3) * HDIM + cb * 32;
            float4 v = *reinterpret_cast<const float4*>(&W[(size_t)(kc + r) * 384 + colbase + c4 * 4]);
            *reinterpret_cast<float4*>(&Bsm[s][r][c4 * 4]) = v;
        }
        __syncthreads();
#pragma unroll
        for (int k = 0; k < 32; ++k) {
            float a_ag[8], a_h[8];
            *reinterpret_cast<float4*>(&a_ag[0]) = *reinterpret_cast<const float4*>(&Agt[k][ty * 8]);
            *reinterpret_cast<float4*>(&a_ag[4]) = *reinterpret_cast<const float4*>(&Agt[k][ty * 8 + 4]);
            *reinterpret_cast<float4*>(&a_h[0])  = *reinterpret_cast<const float4*>(&Ht[k][ty * 8]);
            *reinterpret_cast<float4*>(&a_h[4])  = *reinterpret_cast<const float4*>(&Ht[k][ty * 8 + 4]);
            float b0 = Bsm[0][k][j], b1 = Bsm[1][k][j], b2 = Bsm[2][k][j];
            float b3 = Bsm[3][k][j], b4 = Bsm[4][k][j], b5 = Bsm[5][k][j];
#pragma unroll
            for (int r = 0; r < 8; ++r) {
                acc[0][r] = fmaf(a_ag[r], b0, acc[0][r]);
                acc[1][r] = fmaf(a_ag[r], b1, acc[1][r]);
                acc[2][r] = fmaf(a_ag[r], b2, acc[2][r]);
                acc[3][r] = fmaf(a_h[r],  b3, acc[3][r]);
                acc[4][r] = fmaf(a_h[r],  b4, acc[4][r]);
                acc[5][r] = fmaf(a_h[r],  b5, acc[5][r]);
            }
        }
        __syncthreads();
    }
    const int c0 = cb * 32 + j;
    const float b_ir = bih[c0], b_iz = bih[HDIM + c0], b_in = bih[2 * HDIM + c0];
    const float b_hr = bhh[c0], b_hz = bhh[HDIM + c0], b_hn = bhh[2 * HDIM + c0];
#pragma unroll
    for (int r = 0; r < 8; ++r) {
        int gr = row0 + ty * 8 + r;
        if (gr < M) {
            float gir = acc[0][r] + b_ir, giz = acc[1][r] + b_iz, gin = acc[2][r] + b_in;
            float ghr = acc[3][r] + b_hr, ghz = acc[4][r] + b_hz, ghn = acc[5][r] + b_hn;
            float rg = 1.f / (1.f + expf(-(gir + ghr)));
            float z  = 1.f / (1.f + expf(-(giz + ghz)));
            float nn = tanhf(gin + rg * ghn);
            float hold = h[(size_t)gr * HDIM + c0];
            hout[(size_t)gr * HDIM + c0] = (1.f - z) * nn + z * hold;
        }
    }
}

// ---------------- weight transpose: out[C][R] = in[R][C]^T ------------------
__global__ void transpose_kernel(const float* __restrict__ in, float* __restrict__ out,
                                 int R, int C) {
    int idx = blockIdx.x * 256 + threadIdx.x;
    if (idx < R * C) {
        int r = idx / C, c = idx % C;
        out[(size_t)c * R + r] = in[(size_t)r * C + c];
    }
}

// ---------------- mean-pool + relu per graph --------------------------------
__global__ __launch_bounds__(256) void pool_kernel(const float* __restrict__ h,
                                                   const int* __restrict__ batch,
                                                   float* __restrict__ pooled, int M) {
    __shared__ int lo_s, hi_s;
    __shared__ float sm[256];
    int g = blockIdx.x;
    if (threadIdx.x == 0) {
        int lo = 0, hi = M;
        while (lo < hi) { int mid = (lo + hi) >> 1; if (batch[mid] < g) lo = mid + 1; else hi = mid; }
        lo_s = lo;
        int lo2 = lo, hi2 = M;
        while (lo2 < hi2) { int mid = (lo2 + hi2) >> 1; if (batch[mid] < g + 1) lo2 = mid + 1; else hi2 = mid; }
        hi_s = lo2;
    }
    __syncthreads();
    int lo = lo_s, hi = hi_s;
    int col = threadIdx.x & 127, half = threadIdx.x >> 7;
    float acc = 0.f;
    for (int i = lo + half; i < hi; i += 2) acc += h[(size_t)i * HDIM + col];
    sm[threadIdx.x] = acc;
    __syncthreads();
    if (half == 0) {
        float s = sm[threadIdx.x] + sm[threadIdx.x + 128];
        float c = (float)(hi - lo); if (c < 1.f) c = 1.f;
        pooled[g * HDIM + col] = fmaxf(s / c, 0.f);
    }
}

// ---------------- prediction head -------------------------------------------
__global__ void pred_kernel(const float* __restrict__ pa, const float* __restrict__ pv,
                            const float* __restrict__ pW, const float* __restrict__ pb,
                            float* __restrict__ out) {
    int g = blockIdx.x, lane = threadIdx.x; // 64 threads
    float s = pa[g * HDIM + lane] * pW[lane]
            + pa[g * HDIM + 64 + lane] * pW[64 + lane]
            + pv[g * HDIM + lane] * pW[HDIM + lane]
            + pv[g * HDIM + 64 + lane] * pW[192 + lane];
    for (int off = 32; off; off >>= 1) s += __shfl_down(s, off);
    if (lane == 0) out[g] = s + pb[0];
}

extern "C" void kernel_launch(void* const* d_in, const int* in_sizes, int n_in,
                              void* d_out, int out_size, void* d_ws, size_t ws_size,
                              hipStream_t stream) {
    const float* atom_x   = (const float*)d_in[0];
    const float* voro_x   = (const float*)d_in[1];
    const int*   atom_ei  = (const int*)d_in[2];
    const int*   voro_ei  = (const int*)d_in[3];
    const int*   batch    = (const int*)d_in[4];
    const float* W_at_in  = (const float*)d_in[5];
    const float* W_vo_in  = (const float*)d_in[6];
    const float* atom_W   = (const float*)d_in[7];
    const float* voro_W   = (const float*)d_in[8];
    const float* atom_Wih = (const float*)d_in[9];
    const float* atom_Whh = (const float*)d_in[10];
    const float* atom_bih = (const float*)d_in[11];
    const float* atom_bhh = (const float*)d_in[12];
    const float* voro_Wih = (const float*)d_in[13];
    const float* voro_Whh = (const float*)d_in[14];
    const float* voro_bih = (const float*)d_in[15];
    const float* voro_bhh = (const float*)d_in[16];
    const float* pred_W   = (const float*)d_in[17];
    const float* pred_b   = (const float*)d_in[18];
    float* out = (float*)d_out;

    const int Nn = in_sizes[4];          // 50000 nodes
    const int Ee = in_sizes[2] / 2;      // 600000 edges
    const int Gg = out_size;             // 64 graphs
    const size_t NH = (size_t)Nn * HDIM;

    // workspace carve
    float* X0      = (float*)d_ws;
    float* X1      = X0 + NH;
    float* X2      = X1 + NH;
    float* WihT_a  = X2 + NH;
    float* WhhT_a  = WihT_a + HDIM * 384;
    float* WihT_v  = WhhT_a + HDIM * 384;
    float* WhhT_v  = WihT_v + HDIM * 384;
    float* pooledA = WhhT_v + HDIM * 384;
    float* pooledV = pooledA + Gg * HDIM;
    int*   row_off = (int*)(pooledV + Gg * HDIM);
    int*   cursor  = row_off + (Nn + 1);
    int*   ssrc    = cursor + Nn;

    // transpose GRU weights once per call
    transpose_kernel<<<192, 256, 0, stream>>>(atom_Wih, WihT_a, 384, HDIM);
    transpose_kernel<<<192, 256, 0, stream>>>(atom_Whh, WhhT_a, 384, HDIM);
    transpose_kernel<<<192, 256, 0, stream>>>(voro_Wih, WihT_v, 384, HDIM);
    transpose_kernel<<<192, 256, 0, stream>>>(voro_Whh, WhhT_v, 384, HDIM);

    const float* xs[2]    = {atom_x, voro_x};
    const float* Win[2]   = {W_at_in, W_vo_in};
    const int*   ei[2]    = {atom_ei, voro_ei};
    const float* Wst[2]   = {atom_W, voro_W};
    const float* WihT[2]  = {WihT_a, WihT_v};
    const float* WhhT[2]  = {WhhT_a, WhhT_v};
    const float* bihp[2]  = {atom_bih, voro_bih};
    const float* bhhp[2]  = {atom_bhh, voro_bhh};
    float*       pool2[2] = {pooledA, pooledV};

    const int gemm_mb = (Nn + 127) / 128;
    const int gru_mb  = (Nn + 63) / 64;
    const int eb      = (Ee + 255) / 256;
    const int nb      = (Nn + 255) / 256;
    const int aggb    = (Nn + 3) / 4;

    for (int t = 0; t < 2; ++t) {
        // input embedding: h = tanh(x @ W_in), K=64
        gemm_k<1><<<dim3(gemm_mb, 2), 256, 0, stream>>>(xs[t], Win[t], X0, Nn, 64, HDIM);
        // CSR by destination
        zero_int<<<nb, 256, 0, stream>>>(cursor, Nn);
        hist_kernel<<<eb, 256, 0, stream>>>(ei[t] + Ee, cursor, Ee);
        scan_kernel<<<1, 1024, 0, stream>>>(cursor, row_off, Nn);
        scatter_kernel<<<eb, 256, 0, stream>>>(ei[t], ei[t] + Ee, cursor, ssrc, Ee);

        float* h = X0;
        for (int s = 0; s < 4; ++s) {
            float* mb = (h == X0) ? X1 : X0;
            gemm_k<0><<<dim3(gemm_mb, 2), 256, 0, stream>>>(h, Wst[t] + (size_t)s * HDIM * HDIM, mb, Nn, HDIM, HDIM);
            agg_kernel<<<aggb, 256, 0, stream>>>(mb, row_off, ssrc, X2, Nn);
            gru_kernel<<<dim3(gru_mb, 4), 256, 0, stream>>>(X2, h, WihT[t], WhhT[t], bihp[t], bhhp[t], mb, Nn);
            h = mb;
        }
        pool_kernel<<<Gg, 256, 0, stream>>>(h, batch, pool2[t], Nn);
    }
    pred_kernel<<<Gg, 64, 0, stream>>>(pooledA, pooledV, pred_W, pred_b, out);
}

// Round 2
// 1998.289 us; speedup vs baseline: 1.8553x; 1.8553x over previous
//
#include <hip/hip_runtime.h>
#include <math.h>

#define HDIM 128
typedef unsigned short u16;
typedef __attribute__((ext_vector_type(8))) short bf16x8;
typedef __attribute__((ext_vector_type(4))) float f32x4;

__device__ __forceinline__ u16 f2bf(float x) {
    unsigned u = __float_as_uint(x);
    u = (u + 0x7FFFu + ((u >> 16) & 1u)) >> 16;
    return (u16)u;
}
__device__ __forceinline__ float bf2f(u16 h) {
    return __uint_as_float(((unsigned)h) << 16);
}
__device__ __forceinline__ bf16x8 ld8(const u16* p) {
    return *reinterpret_cast<const bf16x8*>(p);
}
#define MFMA(acc, a, b) acc = __builtin_amdgcn_mfma_f32_16x16x32_bf16(a, b, acc, 0, 0, 0)

// ---------------- weight prep -----------------------------------------------
// WmT[s][r][c] = Wstep[s][c][r]  (B^T for m = h @ W_s), split hi/lo
__global__ __launch_bounds__(256) void prep_wm(const float* __restrict__ W,
                                               u16* __restrict__ hi, u16* __restrict__ lo) {
    int s = blockIdx.y;
    int idx = blockIdx.x * 256 + threadIdx.x;        // 0..16383
    int r = idx >> 7, c = idx & 127;
    float v = W[(size_t)s * 16384 + (size_t)c * 128 + r];
    u16 h = f2bf(v);
    size_t o = (size_t)s * 16384 + (size_t)r * 128 + c;
    hi[o] = h; lo[o] = f2bf(v - bf2f(h));
}

// straight split (Wih/Whh are already B^T = [384][128] row-major)
__global__ __launch_bounds__(256) void prep_split(const float* __restrict__ W,
                                                  u16* __restrict__ hi, u16* __restrict__ lo, int n) {
    int i = blockIdx.x * 256 + threadIdx.x;
    if (i < n) { float v = W[i]; u16 h = f2bf(v); hi[i] = h; lo[i] = f2bf(v - bf2f(h)); }
}

// WinT[r][c] = W_in[c][r], [128][64]
__global__ __launch_bounds__(256) void prep_win(const float* __restrict__ W,
                                                u16* __restrict__ hi, u16* __restrict__ lo) {
    int idx = blockIdx.x * 256 + threadIdx.x;        // 0..8191
    int r = idx >> 6, c = idx & 63;
    float v = W[(size_t)c * 128 + r];
    u16 h = f2bf(v);
    hi[idx] = h; lo[idx] = f2bf(v - bf2f(h));
}

// split x -> padded bf16 hi/lo
__global__ __launch_bounds__(256) void split_x(const float* __restrict__ x,
                                               u16* __restrict__ hi, u16* __restrict__ lo,
                                               int n, int ntot) {
    int i = blockIdx.x * 256 + threadIdx.x;
    if (i >= ntot) return;
    float v = (i < n) ? x[i] : 0.f;
    u16 h = f2bf(v);
    hi[i] = h; lo[i] = f2bf(v - bf2f(h));
}

// ---------------- embed: H = tanh(X @ Win), K=64 ----------------------------
__global__ __launch_bounds__(256) void embed_k(const u16* __restrict__ Xhi, const u16* __restrict__ Xlo,
                                               const u16* __restrict__ Bhi, const u16* __restrict__ Blo,
                                               u16* __restrict__ Hhi, u16* __restrict__ Hlo) {
    const int tid = threadIdx.x, wave = tid >> 6, lane = tid & 63;
    const int row0 = blockIdx.x * 32, cs = wave * 32;
    const int lr = lane & 15, lk = (lane >> 4) * 8;
    f32x4 acc[2][2];
#pragma unroll
    for (int i = 0; i < 2; ++i)
#pragma unroll
        for (int j = 0; j < 2; ++j) acc[i][j] = (f32x4)0.f;
#pragma unroll
    for (int kc = 0; kc < 2; ++kc) {
        const size_t ao = (size_t)(row0 + lr) * 64 + kc * 32 + lk;
        bf16x8 ah0 = ld8(Xhi + ao), ah1 = ld8(Xhi + ao + 16 * 64);
        bf16x8 al0 = ld8(Xlo + ao), al1 = ld8(Xlo + ao + 16 * 64);
#pragma unroll
        for (int cf = 0; cf < 2; ++cf) {
            const size_t bo = (size_t)(cs + cf * 16 + lr) * 64 + kc * 32 + lk;
            bf16x8 bh = ld8(Bhi + bo), bl = ld8(Blo + bo);
            MFMA(acc[0][cf], ah0, bh); MFMA(acc[0][cf], ah0, bl); MFMA(acc[0][cf], al0, bh);
            MFMA(acc[1][cf], ah1, bh); MFMA(acc[1][cf], ah1, bl); MFMA(acc[1][cf], al1, bh);
        }
    }
#pragma unroll
    for (int rf = 0; rf < 2; ++rf)
#pragma unroll
        for (int cf = 0; cf < 2; ++cf)
#pragma unroll
            for (int rg = 0; rg < 4; ++rg) {
                int row = row0 + rf * 16 + (lane >> 4) * 4 + rg;
                int col = cs + cf * 16 + lr;
                float v = tanhf(acc[rf][cf][rg]);
                u16 h = f2bf(v);
                size_t o = (size_t)row * HDIM + col;
                Hhi[o] = h; Hlo[o] = f2bf(v - bf2f(h));
            }
}

// ---------------- m = H @ W_s, K=128 ----------------------------------------
__global__ __launch_bounds__(256) void gemm_m_k(const u16* __restrict__ Ahi, const u16* __restrict__ Alo,
                                                const u16* __restrict__ Bhi, const u16* __restrict__ Blo,
                                                float* __restrict__ Mo) {
    const int tid = threadIdx.x, wave = tid >> 6, lane = tid & 63;
    const int row0 = blockIdx.x * 32, cs = wave * 32;
    const int lr = lane & 15, lk = (lane >> 4) * 8;
    f32x4 acc[2][2];
#pragma unroll
    for (int i = 0; i < 2; ++i)
#pragma unroll
        for (int j = 0; j < 2; ++j) acc[i][j] = (f32x4)0.f;
#pragma unroll
    for (int kc = 0; kc < 4; ++kc) {
        const size_t ao = (size_t)(row0 + lr) * HDIM + kc * 32 + lk;
        bf16x8 ah0 = ld8(Ahi + ao), ah1 = ld8(Ahi + ao + 16 * HDIM);
        bf16x8 al0 = ld8(Alo + ao), al1 = ld8(Alo + ao + 16 * HDIM);
#pragma unroll
        for (int cf = 0; cf < 2; ++cf) {
            const size_t bo = (size_t)(cs + cf * 16 + lr) * HDIM + kc * 32 + lk;
            bf16x8 bh = ld8(Bhi + bo), bl = ld8(Blo + bo);
            MFMA(acc[0][cf], ah0, bh); MFMA(acc[0][cf], ah0, bl); MFMA(acc[0][cf], al0, bh);
            MFMA(acc[1][cf], ah1, bh); MFMA(acc[1][cf], ah1, bl); MFMA(acc[1][cf], al1, bh);
        }
    }
#pragma unroll
    for (int rf = 0; rf < 2; ++rf)
#pragma unroll
        for (int cf = 0; cf < 2; ++cf)
#pragma unroll
            for (int rg = 0; rg < 4; ++rg) {
                int row = row0 + rf * 16 + (lane >> 4) * 4 + rg;
                int col = cs + cf * 16 + lr;
                Mo[(size_t)row * HDIM + col] = acc[rf][cf][rg];
            }
}

// ---------------- edge aggregation: one wave per node, split output ---------
__global__ __launch_bounds__(256) void agg_k(const float* __restrict__ m,
                                             const int* __restrict__ row_off,
                                             const int* __restrict__ ssrc,
                                             u16* __restrict__ AGhi, u16* __restrict__ AGlo,
                                             int Nn, int Npad) {
    int node = (blockIdx.x * 256 + threadIdx.x) >> 6;
    int lane = threadIdx.x & 63;
    if (node >= Npad) return;
    float ax = 0.f, ay = 0.f;
    if (node < Nn) {
        int lo = row_off[node], hi = row_off[node + 1];
        int i = lo;
        for (; i + 3 < hi; i += 4) {
            int s0 = ssrc[i], s1 = ssrc[i + 1], s2 = ssrc[i + 2], s3 = ssrc[i + 3];
            float2 v0 = *reinterpret_cast<const float2*>(m + (size_t)s0 * HDIM + lane * 2);
            float2 v1 = *reinterpret_cast<const float2*>(m + (size_t)s1 * HDIM + lane * 2);
            float2 v2 = *reinterpret_cast<const float2*>(m + (size_t)s2 * HDIM + lane * 2);
            float2 v3 = *reinterpret_cast<const float2*>(m + (size_t)s3 * HDIM + lane * 2);
            ax += v0.x + v1.x + v2.x + v3.x;
            ay += v0.y + v1.y + v2.y + v3.y;
        }
        for (; i < hi; ++i) {
            float2 v = *reinterpret_cast<const float2*>(m + (size_t)ssrc[i] * HDIM + lane * 2);
            ax += v.x; ay += v.y;
        }
    }
    u16 hx = f2bf(ax), hy = f2bf(ay);
    u16 lx = f2bf(ax - bf2f(hx)), ly = f2bf(ay - bf2f(hy));
    *reinterpret_cast<unsigned*>(AGhi + (size_t)node * HDIM + lane * 2) = (unsigned)hx | ((unsigned)hy << 16);
    *reinterpret_cast<unsigned*>(AGlo + (size_t)node * HDIM + lane * 2) = (unsigned)lx | ((unsigned)ly << 16);
}

// ---------------- fused GRU: gi = agg@WihT, gh = h@WhhT, gates --------------
__global__ __launch_bounds__(256) void gru2_k(const u16* __restrict__ AGhi, const u16* __restrict__ AGlo,
                                              const u16* __restrict__ Hhi,  const u16* __restrict__ Hlo,
                                              const u16* __restrict__ Wihi, const u16* __restrict__ Wilo,
                                              const u16* __restrict__ Whhi, const u16* __restrict__ Whlo,
                                              const float* __restrict__ bih, const float* __restrict__ bhh,
                                              u16* __restrict__ Hnhi, u16* __restrict__ Hnlo) {
    const int tid = threadIdx.x, wave = tid >> 6, lane = tid & 63;
    const int row0 = blockIdx.x * 32, cs = wave * 32;
    const int lr = lane & 15, lk = (lane >> 4) * 8;
    f32x4 accI[2][2][3], accH[2][2][3];
#pragma unroll
    for (int a = 0; a < 2; ++a)
#pragma unroll
        for (int b = 0; b < 2; ++b)
#pragma unroll
            for (int g = 0; g < 3; ++g) { accI[a][b][g] = (f32x4)0.f; accH[a][b][g] = (f32x4)0.f; }
#pragma unroll
    for (int kc = 0; kc < 4; ++kc) {
        const size_t ao = (size_t)(row0 + lr) * HDIM + kc * 32 + lk;
        bf16x8 gah0 = ld8(AGhi + ao), gah1 = ld8(AGhi + ao + 16 * HDIM);
        bf16x8 gal0 = ld8(AGlo + ao), gal1 = ld8(AGlo + ao + 16 * HDIM);
        bf16x8 hah0 = ld8(Hhi + ao),  hah1 = ld8(Hhi + ao + 16 * HDIM);
        bf16x8 hal0 = ld8(Hlo + ao),  hal1 = ld8(Hlo + ao + 16 * HDIM);
#pragma unroll
        for (int cf = 0; cf < 2; ++cf)
#pragma unroll
            for (int g = 0; g < 3; ++g) {
                const size_t bo = (size_t)(g * 128 + cs + cf * 16 + lr) * HDIM + kc * 32 + lk;
                bf16x8 bh = ld8(Wihi + bo), bl = ld8(Wilo + bo);
                bf16x8 ch = ld8(Whhi + bo), cl = ld8(Whlo + bo);
                MFMA(accI[0][cf][g], gah0, bh); MFMA(accI[0][cf][g], gah0, bl); MFMA(accI[0][cf][g], gal0, bh);
                MFMA(accI[1][cf][g], gah1, bh); MFMA(accI[1][cf][g], gah1, bl); MFMA(accI[1][cf][g], gal1, bh);
                MFMA(accH[0][cf][g], hah0, ch); MFMA(accH[0][cf][g], hah0, cl); MFMA(accH[0][cf][g], hal0, ch);
                MFMA(accH[1][cf][g], hah1, ch); MFMA(accH[1][cf][g], hah1, cl); MFMA(accH[1][cf][g], hal1, ch);
            }
    }
#pragma unroll
    for (int cf = 0; cf < 2; ++cf) {
        const int c = cs + cf * 16 + lr;
        const float bir = bih[c], biz = bih[128 + c], bin = bih[256 + c];
        const float bhr = bhh[c], bhz = bhh[128 + c], bhn = bhh[256 + c];
#pragma unroll
        for (int rf = 0; rf < 2; ++rf)
#pragma unroll
            for (int rg = 0; rg < 4; ++rg) {
                const int row = row0 + rf * 16 + (lane >> 4) * 4 + rg;
                float gir = accI[rf][cf][0][rg] + bir;
                float giz = accI[rf][cf][1][rg] + biz;
                float gin = accI[rf][cf][2][rg] + bin;
                float ghr = accH[rf][cf][0][rg] + bhr;
                float ghz = accH[rf][cf][1][rg] + bhz;
                float ghn = accH[rf][cf][2][rg] + bhn;
                float r = 1.f / (1.f + expf(-(gir + ghr)));
                float z = 1.f / (1.f + expf(-(giz + ghz)));
                float nn = tanhf(gin + r * ghn);
                size_t o = (size_t)row * HDIM + c;
                float hold = bf2f(Hhi[o]) + bf2f(Hlo[o]);
                float hn = (1.f - z) * nn + z * hold;
                u16 hh = f2bf(hn);
                Hnhi[o] = hh; Hnlo[o] = f2bf(hn - bf2f(hh));
            }
    }
}

// ---------------- CSR build -------------------------------------------------
__global__ void zero_int(int* p, int n) {
    int i = blockIdx.x * 256 + threadIdx.x;
    if (i < n) p[i] = 0;
}

__global__ void hist_kernel(const int* __restrict__ dst, int* __restrict__ cnt, int E) {
    int e = blockIdx.x * 256 + threadIdx.x;
    if (e < E) atomicAdd(&cnt[dst[e]], 1);
}

__global__ __launch_bounds__(1024) void scan_kernel(int* __restrict__ cnt_cursor,
                                                    int* __restrict__ row_off, int n) {
    __shared__ int sm[1024];
    __shared__ int carry_s;
    const int tid = threadIdx.x;
    if (tid == 0) carry_s = 0;
    __syncthreads();
    for (int base = 0; base < n; base += 1024) {
        int i = base + tid;
        int v = (i < n) ? cnt_cursor[i] : 0;
        sm[tid] = v;
        __syncthreads();
        for (int off = 1; off < 1024; off <<= 1) {
            int t = (tid >= off) ? sm[tid - off] : 0;
            __syncthreads();
            sm[tid] += t;
            __syncthreads();
        }
        int excl = sm[tid] - v;
        int carry = carry_s;
        int total = sm[1023];
        if (i < n) { row_off[i] = carry + excl; cnt_cursor[i] = carry + excl; }
        __syncthreads();
        if (tid == 0) carry_s = carry + total;
        __syncthreads();
    }
    if (tid == 0) row_off[n] = carry_s;
}

__global__ void scatter_kernel(const int* __restrict__ src, const int* __restrict__ dst,
                               int* __restrict__ cursor, int* __restrict__ ssrc, int E) {
    int e = blockIdx.x * 256 + threadIdx.x;
    if (e < E) {
        int p = atomicAdd(&cursor[dst[e]], 1);
        ssrc[p] = src[e];
    }
}

// ---------------- mean-pool + relu ------------------------------------------
__global__ __launch_bounds__(256) void pool_k(const u16* __restrict__ Hhi, const u16* __restrict__ Hlo,
                                              const int* __restrict__ batch,
                                              float* __restrict__ pooled, int M) {
    __shared__ int lo_s, hi_s;
    __shared__ float smx[256], smy[256];
    int g = blockIdx.x;
    if (threadIdx.x == 0) {
        int lo = 0, hi = M;
        while (lo < hi) { int mid = (lo + hi) >> 1; if (batch[mid] < g) lo = mid + 1; else hi = mid; }
        lo_s = lo;
        int lo2 = lo, hi2 = M;
        while (lo2 < hi2) { int mid = (lo2 + hi2) >> 1; if (batch[mid] < g + 1) lo2 = mid + 1; else hi2 = mid; }
        hi_s = lo2;
    }
    __syncthreads();
    int lo = lo_s, hi = hi_s;
    int c2 = threadIdx.x & 63, quarter = threadIdx.x >> 6;
    float ax = 0.f, ay = 0.f;
    for (int i = lo + quarter; i < hi; i += 4) {
        unsigned uh = *reinterpret_cast<const unsigned*>(Hhi + (size_t)i * HDIM + c2 * 2);
        unsigned ul = *reinterpret_cast<const unsigned*>(Hlo + (size_t)i * HDIM + c2 * 2);
        ax += bf2f((u16)(uh & 0xFFFF)) + bf2f((u16)(ul & 0xFFFF));
        ay += bf2f((u16)(uh >> 16)) + bf2f((u16)(ul >> 16));
    }
    smx[threadIdx.x] = ax; smy[threadIdx.x] = ay;
    __syncthreads();
    if (quarter == 0) {
        float sx = smx[c2] + smx[c2 + 64] + smx[c2 + 128] + smx[c2 + 192];
        float sy = smy[c2] + smy[c2 + 64] + smy[c2 + 128] + smy[c2 + 192];
        float cnt = (float)(hi - lo); if (cnt < 1.f) cnt = 1.f;
        pooled[g * HDIM + c2 * 2]     = fmaxf(sx / cnt, 0.f);
        pooled[g * HDIM + c2 * 2 + 1] = fmaxf(sy / cnt, 0.f);
    }
}

// ---------------- prediction head -------------------------------------------
__global__ void pred_kernel(const float* __restrict__ pa, const float* __restrict__ pv,
                            const float* __restrict__ pW, const float* __restrict__ pb,
                            float* __restrict__ out) {
    int g = blockIdx.x, lane = threadIdx.x; // 64 threads
    float s = pa[g * HDIM + lane] * pW[lane]
            + pa[g * HDIM + 64 + lane] * pW[64 + lane]
            + pv[g * HDIM + lane] * pW[HDIM + lane]
            + pv[g * HDIM + 64 + lane] * pW[192 + lane];
    for (int off = 32; off; off >>= 1) s += __shfl_down(s, off);
    if (lane == 0) out[g] = s + pb[0];
}

extern "C" void kernel_launch(void* const* d_in, const int* in_sizes, int n_in,
                              void* d_out, int out_size, void* d_ws, size_t ws_size,
                              hipStream_t stream) {
    const float* atom_x   = (const float*)d_in[0];
    const float* voro_x   = (const float*)d_in[1];
    const int*   atom_ei  = (const int*)d_in[2];
    const int*   voro_ei  = (const int*)d_in[3];
    const int*   batch    = (const int*)d_in[4];
    const float* W_at_in  = (const float*)d_in[5];
    const float* W_vo_in  = (const float*)d_in[6];
    const float* atom_W   = (const float*)d_in[7];
    const float* voro_W   = (const float*)d_in[8];
    const float* atom_Wih = (const float*)d_in[9];
    const float* atom_Whh = (const float*)d_in[10];
    const float* atom_bih = (const float*)d_in[11];
    const float* atom_bhh = (const float*)d_in[12];
    const float* voro_Wih = (const float*)d_in[13];
    const float* voro_Whh = (const float*)d_in[14];
    const float* voro_bih = (const float*)d_in[15];
    const float* voro_bhh = (const float*)d_in[16];
    const float* pred_W   = (const float*)d_in[17];
    const float* pred_b   = (const float*)d_in[18];
    float* out = (float*)d_out;

    const int Nn = in_sizes[4];
    const int Ee = in_sizes[2] / 2;
    const int Gg = out_size;
    const int Npad = (Nn + 127) & ~127;

    char* base = (char*)d_ws;
    size_t off = 0;
    auto alloc = [&](size_t bytes) -> char* {
        char* p = base + off;
        off = (off + bytes + 255) & ~(size_t)255;
        return p;
    };

    float* m_buf = (float*)alloc((size_t)Npad * HDIM * 4);
    u16* Hhi  = (u16*)alloc((size_t)Npad * HDIM * 2);
    u16* Hlo  = (u16*)alloc((size_t)Npad * HDIM * 2);
    u16* Hnhi = (u16*)alloc((size_t)Npad * HDIM * 2);
    u16* Hnlo = (u16*)alloc((size_t)Npad * HDIM * 2);
    u16* AGhi = (u16*)alloc((size_t)Npad * HDIM * 2);
    u16* AGlo = (u16*)alloc((size_t)Npad * HDIM * 2);
    u16* WmHi[2], *WmLo[2], *WiHi[2], *WiLo[2], *WhHi[2], *WhLo[2], *WnHi[2], *WnLo[2];
    for (int t = 0; t < 2; ++t) {
        WmHi[t] = (u16*)alloc(4 * 16384 * 2); WmLo[t] = (u16*)alloc(4 * 16384 * 2);
        WiHi[t] = (u16*)alloc(384 * 128 * 2); WiLo[t] = (u16*)alloc(384 * 128 * 2);
        WhHi[t] = (u16*)alloc(384 * 128 * 2); WhLo[t] = (u16*)alloc(384 * 128 * 2);
        WnHi[t] = (u16*)alloc(128 * 64 * 2);  WnLo[t] = (u16*)alloc(128 * 64 * 2);
    }
    float* pooledA = (float*)alloc((size_t)Gg * HDIM * 4);
    float* pooledV = (float*)alloc((size_t)Gg * HDIM * 4);
    int* row_off = (int*)alloc((size_t)(Nn + 1) * 4);
    int* cursor  = (int*)alloc((size_t)Nn * 4);
    int* ssrc    = (int*)alloc((size_t)Ee * 4);
    // x hi/lo alias m_buf (x consumed by embed before m is first written)
    u16* Xhi = (u16*)m_buf;
    u16* Xlo = Xhi + (size_t)Npad * 64;

    const float* xs[2]   = {atom_x, voro_x};
    const float* Win[2]  = {W_at_in, W_vo_in};
    const int*   ei[2]   = {atom_ei, voro_ei};
    const float* Wst[2]  = {atom_W, voro_W};
    const float* Wih[2]  = {atom_Wih, voro_Wih};
    const float* Whh[2]  = {atom_Whh, voro_Whh};
    const float* bihp[2] = {atom_bih, voro_bih};
    const float* bhhp[2] = {atom_bhh, voro_bhh};
    float* pool2[2]      = {pooledA, pooledV};

    // weight prep
    for (int t = 0; t < 2; ++t) {
        prep_wm<<<dim3(64, 4), 256, 0, stream>>>(Wst[t], WmHi[t], WmLo[t]);
        prep_split<<<192, 256, 0, stream>>>(Wih[t], WiHi[t], WiLo[t], 384 * 128);
        prep_split<<<192, 256, 0, stream>>>(Whh[t], WhHi[t], WhLo[t], 384 * 128);
        prep_win<<<32, 256, 0, stream>>>(Win[t], WnHi[t], WnLo[t]);
    }

    const int eb = (Ee + 255) / 256;
    const int nb = (Nn + 255) / 256;
    const int gb = Npad / 32;
    const int ab = Npad / 4;

    for (int t = 0; t < 2; ++t) {
        split_x<<<(Npad * 64 + 255) / 256, 256, 0, stream>>>(xs[t], Xhi, Xlo, Nn * 64, Npad * 64);
        embed_k<<<gb, 256, 0, stream>>>(Xhi, Xlo, WnHi[t], WnLo[t], Hhi, Hlo);

        zero_int<<<nb, 256, 0, stream>>>(cursor, Nn);
        hist_kernel<<<eb, 256, 0, stream>>>(ei[t] + Ee, cursor, Ee);
        scan_kernel<<<1, 1024, 0, stream>>>(cursor, row_off, Nn);
        scatter_kernel<<<eb, 256, 0, stream>>>(ei[t], ei[t] + Ee, cursor, ssrc, Ee);

        u16 *hA = Hhi, *hB = Hlo, *nA = Hnhi, *nB = Hnlo;
        for (int s = 0; s < 4; ++s) {
            gemm_m_k<<<gb, 256, 0, stream>>>(hA, hB, WmHi[t] + (size_t)s * 16384,
                                             WmLo[t] + (size_t)s * 16384, m_buf);
            agg_k<<<ab, 256, 0, stream>>>(m_buf, row_off, ssrc, AGhi, AGlo, Nn, Npad);
            gru2_k<<<gb, 256, 0, stream>>>(AGhi, AGlo, hA, hB, WiHi[t], WiLo[t],
                                           WhHi[t], WhLo[t], bihp[t], bhhp[t], nA, nB);
            u16* tp;
            tp = hA; hA = nA; nA = tp;
            tp = hB; hB = nB; nB = tp;
        }
        pool_k<<<Gg, 256, 0, stream>>>(hA, hB, batch, pool2[t], Nn);
    }
    pred_kernel<<<Gg, 64, 0, stream>>>(pooledA, pooledV, pred_W, pred_b, out);
}

// Round 3
// 1868.123 us; speedup vs baseline: 1.9846x; 1.0697x over previous
//
#include <hip/hip_runtime.h>
#include <math.h>

#define HDIM 128
typedef unsigned short u16;
typedef __attribute__((ext_vector_type(8))) short bf16x8;
typedef __attribute__((ext_vector_type(4))) float f32x4;

__device__ __forceinline__ u16 f2bf(float x) {
    unsigned u = __float_as_uint(x);
    u = (u + 0x7FFFu + ((u >> 16) & 1u)) >> 16;
    return (u16)u;
}
__device__ __forceinline__ float bf2f(u16 h) {
    return __uint_as_float(((unsigned)h) << 16);
}
__device__ __forceinline__ bf16x8 ld8(const u16* p) {
    return *reinterpret_cast<const bf16x8*>(p);
}
#define MFMA(acc, a, b) acc = __builtin_amdgcn_mfma_f32_16x16x32_bf16(a, b, acc, 0, 0, 0)

// ---------------- weight prep -----------------------------------------------
// Wfull[s][r][c2] = dot(Ws[s][r][:], Wih[c2][:])  (since gi = (hagg@Ws)@Wih^T)
// stored as B^T layout: out[s][c2][r], split hi/lo
__global__ __launch_bounds__(256) void prep_wfull(const float* __restrict__ Ws,
                                                  const float* __restrict__ Wih,
                                                  u16* __restrict__ hi, u16* __restrict__ lo) {
    int s = blockIdx.y;
    int idx = blockIdx.x * 256 + threadIdx.x;   // [0, 49152)
    int c2 = idx >> 7, r = idx & 127;
    const float* wr = Ws + (size_t)s * 16384 + (size_t)r * 128;
    const float* wc = Wih + (size_t)c2 * 128;
    float acc = 0.f;
#pragma unroll 8
    for (int k = 0; k < 128; k += 4) {
        float4 a = *reinterpret_cast<const float4*>(wr + k);
        float4 b = *reinterpret_cast<const float4*>(wc + k);
        acc += a.x * b.x + a.y * b.y + a.z * b.z + a.w * b.w;
    }
    size_t o = (size_t)s * 49152 + idx;
    u16 h = f2bf(acc);
    hi[o] = h; lo[o] = f2bf(acc - bf2f(h));
}

// straight split (Whh is already B^T = [384][128] row-major)
__global__ __launch_bounds__(256) void prep_split(const float* __restrict__ W,
                                                  u16* __restrict__ hi, u16* __restrict__ lo, int n) {
    int i = blockIdx.x * 256 + threadIdx.x;
    if (i < n) { float v = W[i]; u16 h = f2bf(v); hi[i] = h; lo[i] = f2bf(v - bf2f(h)); }
}

// WinT[r][c] = W_in[c][r], [128][64]
__global__ __launch_bounds__(256) void prep_win(const float* __restrict__ W,
                                                u16* __restrict__ hi, u16* __restrict__ lo) {
    int idx = blockIdx.x * 256 + threadIdx.x;        // 0..8191
    int r = idx >> 6, c = idx & 63;
    float v = W[(size_t)c * 128 + r];
    u16 h = f2bf(v);
    hi[idx] = h; lo[idx] = f2bf(v - bf2f(h));
}

// split x -> padded bf16 hi/lo
__global__ __launch_bounds__(256) void split_x(const float* __restrict__ x,
                                               u16* __restrict__ hi, u16* __restrict__ lo,
                                               int n, int ntot) {
    int i = blockIdx.x * 256 + threadIdx.x;
    if (i >= ntot) return;
    float v = (i < n) ? x[i] : 0.f;
    u16 h = f2bf(v);
    hi[i] = h; lo[i] = f2bf(v - bf2f(h));
}

// ---------------- embed: H = tanh(X @ Win), K=64 ----------------------------
__global__ __launch_bounds__(256) void embed_k(const u16* __restrict__ Xhi, const u16* __restrict__ Xlo,
                                               const u16* __restrict__ Bhi, const u16* __restrict__ Blo,
                                               u16* __restrict__ Hhi, u16* __restrict__ Hlo) {
    const int tid = threadIdx.x, wave = tid >> 6, lane = tid & 63;
    const int row0 = blockIdx.x * 32, cs = wave * 32;
    const int lr = lane & 15, lk = (lane >> 4) * 8;
    f32x4 acc[2][2];
#pragma unroll
    for (int i = 0; i < 2; ++i)
#pragma unroll
        for (int j = 0; j < 2; ++j) acc[i][j] = (f32x4)0.f;
#pragma unroll
    for (int kc = 0; kc < 2; ++kc) {
        const size_t ao = (size_t)(row0 + lr) * 64 + kc * 32 + lk;
        bf16x8 ah0 = ld8(Xhi + ao), ah1 = ld8(Xhi + ao + 16 * 64);
        bf16x8 al0 = ld8(Xlo + ao), al1 = ld8(Xlo + ao + 16 * 64);
#pragma unroll
        for (int cf = 0; cf < 2; ++cf) {
            const size_t bo = (size_t)(cs + cf * 16 + lr) * 64 + kc * 32 + lk;
            bf16x8 bh = ld8(Bhi + bo), bl = ld8(Blo + bo);
            MFMA(acc[0][cf], ah0, bh); MFMA(acc[0][cf], ah0, bl); MFMA(acc[0][cf], al0, bh);
            MFMA(acc[1][cf], ah1, bh); MFMA(acc[1][cf], ah1, bl); MFMA(acc[1][cf], al1, bh);
        }
    }
#pragma unroll
    for (int rf = 0; rf < 2; ++rf)
#pragma unroll
        for (int cf = 0; cf < 2; ++cf)
#pragma unroll
            for (int rg = 0; rg < 4; ++rg) {
                int row = row0 + rf * 16 + (lane >> 4) * 4 + rg;
                int col = cs + cf * 16 + lr;
                float v = tanhf(acc[rf][cf][rg]);
                u16 h = f2bf(v);
                size_t o = (size_t)row * HDIM + col;
                Hhi[o] = h; Hlo[o] = f2bf(v - bf2f(h));
            }
}

// ---------------- edge aggregation of h: one wave per node ------------------
__global__ __launch_bounds__(256) void hagg_k(const u16* __restrict__ Hhi, const u16* __restrict__ Hlo,
                                              const int* __restrict__ row_off,
                                              const int* __restrict__ ssrc,
                                              u16* __restrict__ AGhi, u16* __restrict__ AGlo,
                                              int Nn, int Npad) {
    int node = (blockIdx.x * 256 + threadIdx.x) >> 6;
    int lane = threadIdx.x & 63;
    if (node >= Npad) return;
    float ax = 0.f, ay = 0.f;
    if (node < Nn) {
        int lo = row_off[node], hi = row_off[node + 1];
        int i = lo;
        for (; i + 3 < hi; i += 4) {
            int s0 = ssrc[i], s1 = ssrc[i + 1], s2 = ssrc[i + 2], s3 = ssrc[i + 3];
            unsigned h0 = *reinterpret_cast<const unsigned*>(Hhi + (size_t)s0 * HDIM + lane * 2);
            unsigned l0 = *reinterpret_cast<const unsigned*>(Hlo + (size_t)s0 * HDIM + lane * 2);
            unsigned h1 = *reinterpret_cast<const unsigned*>(Hhi + (size_t)s1 * HDIM + lane * 2);
            unsigned l1 = *reinterpret_cast<const unsigned*>(Hlo + (size_t)s1 * HDIM + lane * 2);
            unsigned h2 = *reinterpret_cast<const unsigned*>(Hhi + (size_t)s2 * HDIM + lane * 2);
            unsigned l2 = *reinterpret_cast<const unsigned*>(Hlo + (size_t)s2 * HDIM + lane * 2);
            unsigned h3 = *reinterpret_cast<const unsigned*>(Hhi + (size_t)s3 * HDIM + lane * 2);
            unsigned l3 = *reinterpret_cast<const unsigned*>(Hlo + (size_t)s3 * HDIM + lane * 2);
            ax += bf2f((u16)h0) + bf2f((u16)l0) + bf2f((u16)h1) + bf2f((u16)l1)
                + bf2f((u16)h2) + bf2f((u16)l2) + bf2f((u16)h3) + bf2f((u16)l3);
            ay += bf2f((u16)(h0 >> 16)) + bf2f((u16)(l0 >> 16)) + bf2f((u16)(h1 >> 16)) + bf2f((u16)(l1 >> 16))
                + bf2f((u16)(h2 >> 16)) + bf2f((u16)(l2 >> 16)) + bf2f((u16)(h3 >> 16)) + bf2f((u16)(l3 >> 16));
        }
        for (; i < hi; ++i) {
            int s = ssrc[i];
            unsigned h = *reinterpret_cast<const unsigned*>(Hhi + (size_t)s * HDIM + lane * 2);
            unsigned l = *reinterpret_cast<const unsigned*>(Hlo + (size_t)s * HDIM + lane * 2);
            ax += bf2f((u16)h) + bf2f((u16)l);
            ay += bf2f((u16)(h >> 16)) + bf2f((u16)(l >> 16));
        }
    }
    u16 hx = f2bf(ax), hy = f2bf(ay);
    u16 lx = f2bf(ax - bf2f(hx)), ly = f2bf(ay - bf2f(hy));
    *reinterpret_cast<unsigned*>(AGhi + (size_t)node * HDIM + lane * 2) = (unsigned)hx | ((unsigned)hy << 16);
    *reinterpret_cast<unsigned*>(AGlo + (size_t)node * HDIM + lane * 2) = (unsigned)lx | ((unsigned)ly << 16);
}

// ---------------- fused GRU: gi = hagg@WfullT, gh = h@WhhT, gates -----------
// 512 threads = 8 waves; wave w: rows row0..row0+64 (4 frags), cols w*16..w*16+16
__global__ __launch_bounds__(512, 2) void gru3_k(const u16* __restrict__ AGhi, const u16* __restrict__ AGlo,
                                                 const u16* __restrict__ Hhi,  const u16* __restrict__ Hlo,
                                                 const u16* __restrict__ Wfhi, const u16* __restrict__ Wflo,
                                                 const u16* __restrict__ Whhi, const u16* __restrict__ Whlo,
                                                 const float* __restrict__ bih, const float* __restrict__ bhh,
                                                 u16* __restrict__ Hnhi, u16* __restrict__ Hnlo) {
    const int tid = threadIdx.x, wave = tid >> 6, lane = tid & 63;
    const int row0 = blockIdx.x * 64;
    const int cs = wave * 16;
    const int lr = lane & 15, lk = (lane >> 4) * 8;
    f32x4 accI[4][3], accH[4][3];
#pragma unroll
    for (int rf = 0; rf < 4; ++rf)
#pragma unroll
        for (int g = 0; g < 3; ++g) { accI[rf][g] = (f32x4)0.f; accH[rf][g] = (f32x4)0.f; }
#pragma unroll
    for (int kc = 0; kc < 4; ++kc) {
        bf16x8 ga[4], gl[4], ha[4], hl[4];
#pragma unroll
        for (int rf = 0; rf < 4; ++rf) {
            const size_t ao = (size_t)(row0 + rf * 16 + lr) * HDIM + kc * 32 + lk;
            ga[rf] = ld8(AGhi + ao); gl[rf] = ld8(AGlo + ao);
            ha[rf] = ld8(Hhi + ao);  hl[rf] = ld8(Hlo + ao);
        }
#pragma unroll
        for (int g = 0; g < 3; ++g) {
            const size_t bo = (size_t)(g * 128 + cs + lr) * HDIM + kc * 32 + lk;
            bf16x8 fh = ld8(Wfhi + bo), fl = ld8(Wflo + bo);
            bf16x8 wh = ld8(Whhi + bo), wl = ld8(Whlo + bo);
#pragma unroll
            for (int rf = 0; rf < 4; ++rf) {
                MFMA(accI[rf][g], ga[rf], fh); MFMA(accI[rf][g], ga[rf], fl); MFMA(accI[rf][g], gl[rf], fh);
                MFMA(accH[rf][g], ha[rf], wh); MFMA(accH[rf][g], ha[rf], wl); MFMA(accH[rf][g], hl[rf], wh);
            }
        }
    }
    const int c = cs + lr;
    const float bir = bih[c], biz = bih[128 + c], bin = bih[256 + c];
    const float bhr = bhh[c], bhz = bhh[128 + c], bhn = bhh[256 + c];
#pragma unroll
    for (int rf = 0; rf < 4; ++rf)
#pragma unroll
        for (int rg = 0; rg < 4; ++rg) {
            const int row = row0 + rf * 16 + (lane >> 4) * 4 + rg;
            float gir = accI[rf][0][rg] + bir;
            float giz = accI[rf][1][rg] + biz;
            float gin = accI[rf][2][rg] + bin;
            float ghr = accH[rf][0][rg] + bhr;
            float ghz = accH[rf][1][rg] + bhz;
            float ghn = accH[rf][2][rg] + bhn;
            float r = 1.f / (1.f + expf(-(gir + ghr)));
            float z = 1.f / (1.f + expf(-(giz + ghz)));
            float nn = tanhf(gin + r * ghn);
            size_t o = (size_t)row * HDIM + c;
            float hold = bf2f(Hhi[o]) + bf2f(Hlo[o]);
            float hn = (1.f - z) * nn + z * hold;
            u16 hh = f2bf(hn);
            Hnhi[o] = hh; Hnlo[o] = f2bf(hn - bf2f(hh));
        }
}

// ---------------- CSR build -------------------------------------------------
__global__ void zero_int(int* p, int n) {
    int i = blockIdx.x * 256 + threadIdx.x;
    if (i < n) p[i] = 0;
}

__global__ void hist_kernel(const int* __restrict__ dst, int* __restrict__ cnt, int E) {
    int e = blockIdx.x * 256 + threadIdx.x;
    if (e < E) atomicAdd(&cnt[dst[e]], 1);
}

__global__ __launch_bounds__(1024) void scan_kernel(int* __restrict__ cnt_cursor,
                                                    int* __restrict__ row_off, int n) {
    __shared__ int sm[1024];
    __shared__ int carry_s;
    const int tid = threadIdx.x;
    if (tid == 0) carry_s = 0;
    __syncthreads();
    for (int base = 0; base < n; base += 1024) {
        int i = base + tid;
        int v = (i < n) ? cnt_cursor[i] : 0;
        sm[tid] = v;
        __syncthreads();
        for (int off = 1; off < 1024; off <<= 1) {
            int t = (tid >= off) ? sm[tid - off] : 0;
            __syncthreads();
            sm[tid] += t;
            __syncthreads();
        }
        int excl = sm[tid] - v;
        int carry = carry_s;
        int total = sm[1023];
        if (i < n) { row_off[i] = carry + excl; cnt_cursor[i] = carry + excl; }
        __syncthreads();
        if (tid == 0) carry_s = carry + total;
        __syncthreads();
    }
    if (tid == 0) row_off[n] = carry_s;
}

__global__ void scatter_kernel(const int* __restrict__ src, const int* __restrict__ dst,
                               int* __restrict__ cursor, int* __restrict__ ssrc, int E) {
    int e = blockIdx.x * 256 + threadIdx.x;
    if (e < E) {
        int p = atomicAdd(&cursor[dst[e]], 1);
        ssrc[p] = src[e];
    }
}

// ---------------- mean-pool + relu ------------------------------------------
__global__ __launch_bounds__(256) void pool_k(const u16* __restrict__ Hhi, const u16* __restrict__ Hlo,
                                              const int* __restrict__ batch,
                                              float* __restrict__ pooled, int M) {
    __shared__ int lo_s, hi_s;
    __shared__ float smx[256], smy[256];
    int g = blockIdx.x;
    if (threadIdx.x == 0) {
        int lo = 0, hi = M;
        while (lo < hi) { int mid = (lo + hi) >> 1; if (batch[mid] < g) lo = mid + 1; else hi = mid; }
        lo_s = lo;
        int lo2 = lo, hi2 = M;
        while (lo2 < hi2) { int mid = (lo2 + hi2) >> 1; if (batch[mid] < g + 1) lo2 = mid + 1; else hi2 = mid; }
        hi_s = lo2;
    }
    __syncthreads();
    int lo = lo_s, hi = hi_s;
    int c2 = threadIdx.x & 63, quarter = threadIdx.x >> 6;
    float ax = 0.f, ay = 0.f;
    for (int i = lo + quarter; i < hi; i += 4) {
        unsigned uh = *reinterpret_cast<const unsigned*>(Hhi + (size_t)i * HDIM + c2 * 2);
        unsigned ul = *reinterpret_cast<const unsigned*>(Hlo + (size_t)i * HDIM + c2 * 2);
        ax += bf2f((u16)(uh & 0xFFFF)) + bf2f((u16)(ul & 0xFFFF));
        ay += bf2f((u16)(uh >> 16)) + bf2f((u16)(ul >> 16));
    }
    smx[threadIdx.x] = ax; smy[threadIdx.x] = ay;
    __syncthreads();
    if (quarter == 0) {
        float sx = smx[c2] + smx[c2 + 64] + smx[c2 + 128] + smx[c2 + 192];
        float sy = smy[c2] + smy[c2 + 64] + smy[c2 + 128] + smy[c2 + 192];
        float cnt = (float)(hi - lo); if (cnt < 1.f) cnt = 1.f;
        pooled[g * HDIM + c2 * 2]     = fmaxf(sx / cnt, 0.f);
        pooled[g * HDIM + c2 * 2 + 1] = fmaxf(sy / cnt, 0.f);
    }
}

// ---------------- prediction head -------------------------------------------
__global__ void pred_kernel(const float* __restrict__ pa, const float* __restrict__ pv,
                            const float* __restrict__ pW, const float* __restrict__ pb,
                            float* __restrict__ out) {
    int g = blockIdx.x, lane = threadIdx.x; // 64 threads
    float s = pa[g * HDIM + lane] * pW[lane]
            + pa[g * HDIM + 64 + lane] * pW[64 + lane]
            + pv[g * HDIM + lane] * pW[HDIM + lane]
            + pv[g * HDIM + 64 + lane] * pW[192 + lane];
    for (int off = 32; off; off >>= 1) s += __shfl_down(s, off);
    if (lane == 0) out[g] = s + pb[0];
}

extern "C" void kernel_launch(void* const* d_in, const int* in_sizes, int n_in,
                              void* d_out, int out_size, void* d_ws, size_t ws_size,
                              hipStream_t stream) {
    const float* atom_x   = (const float*)d_in[0];
    const float* voro_x   = (const float*)d_in[1];
    const int*   atom_ei  = (const int*)d_in[2];
    const int*   voro_ei  = (const int*)d_in[3];
    const int*   batch    = (const int*)d_in[4];
    const float* W_at_in  = (const float*)d_in[5];
    const float* W_vo_in  = (const float*)d_in[6];
    const float* atom_W   = (const float*)d_in[7];
    const float* voro_W   = (const float*)d_in[8];
    const float* atom_Wih = (const float*)d_in[9];
    const float* atom_Whh = (const float*)d_in[10];
    const float* atom_bih = (const float*)d_in[11];
    const float* atom_bhh = (const float*)d_in[12];
    const float* voro_Wih = (const float*)d_in[13];
    const float* voro_Whh = (const float*)d_in[14];
    const float* voro_bih = (const float*)d_in[15];
    const float* voro_bhh = (const float*)d_in[16];
    const float* pred_W   = (const float*)d_in[17];
    const float* pred_b   = (const float*)d_in[18];
    float* out = (float*)d_out;

    const int Nn = in_sizes[4];
    const int Ee = in_sizes[2] / 2;
    const int Gg = out_size;
    const int Npad = (Nn + 63) & ~63;

    char* base = (char*)d_ws;
    size_t off = 0;
    auto alloc = [&](size_t bytes) -> char* {
        char* p = base + off;
        off = (off + bytes + 255) & ~(size_t)255;
        return p;
    };

    u16* Hhi  = (u16*)alloc((size_t)Npad * HDIM * 2);
    u16* Hlo  = (u16*)alloc((size_t)Npad * HDIM * 2);
    u16* Hnhi = (u16*)alloc((size_t)Npad * HDIM * 2);
    u16* Hnlo = (u16*)alloc((size_t)Npad * HDIM * 2);
    u16* AGhi = (u16*)alloc((size_t)Npad * HDIM * 2);
    u16* AGlo = (u16*)alloc((size_t)Npad * HDIM * 2);
    u16* Xhi  = (u16*)alloc((size_t)Npad * 64 * 2);
    u16* Xlo  = (u16*)alloc((size_t)Npad * 64 * 2);
    u16 *WfHi[2], *WfLo[2], *WhHi[2], *WhLo[2], *WnHi[2], *WnLo[2];
    for (int t = 0; t < 2; ++t) {
        WfHi[t] = (u16*)alloc(4 * 49152 * 2); WfLo[t] = (u16*)alloc(4 * 49152 * 2);
        WhHi[t] = (u16*)alloc(384 * 128 * 2); WhLo[t] = (u16*)alloc(384 * 128 * 2);
        WnHi[t] = (u16*)alloc(128 * 64 * 2);  WnLo[t] = (u16*)alloc(128 * 64 * 2);
    }
    float* pooledA = (float*)alloc((size_t)Gg * HDIM * 4);
    float* pooledV = (float*)alloc((size_t)Gg * HDIM * 4);
    int* row_off = (int*)alloc((size_t)(Nn + 1) * 4);
    int* cursor  = (int*)alloc((size_t)Nn * 4);
    int* ssrc    = (int*)alloc((size_t)Ee * 4);

    const float* xs[2]   = {atom_x, voro_x};
    const float* Win[2]  = {W_at_in, W_vo_in};
    const int*   ei[2]   = {atom_ei, voro_ei};
    const float* Wst[2]  = {atom_W, voro_W};
    const float* Wih[2]  = {atom_Wih, voro_Wih};
    const float* Whh[2]  = {atom_Whh, voro_Whh};
    const float* bihp[2] = {atom_bih, voro_bih};
    const float* bhhp[2] = {atom_bhh, voro_bhh};
    float* pool2[2]      = {pooledA, pooledV};

    // weight prep
    for (int t = 0; t < 2; ++t) {
        prep_wfull<<<dim3(192, 4), 256, 0, stream>>>(Wst[t], Wih[t], WfHi[t], WfLo[t]);
        prep_split<<<192, 256, 0, stream>>>(Whh[t], WhHi[t], WhLo[t], 384 * 128);
        prep_win<<<32, 256, 0, stream>>>(Win[t], WnHi[t], WnLo[t]);
    }

    const int eb = (Ee + 255) / 256;
    const int nb = (Nn + 255) / 256;
    const int gbe = Npad / 32;
    const int gbg = Npad / 64;
    const int ab = Npad / 4;

    for (int t = 0; t < 2; ++t) {
        split_x<<<(Npad * 64 + 255) / 256, 256, 0, stream>>>(xs[t], Xhi, Xlo, Nn * 64, Npad * 64);
        embed_k<<<gbe, 256, 0, stream>>>(Xhi, Xlo, WnHi[t], WnLo[t], Hhi, Hlo);

        zero_int<<<nb, 256, 0, stream>>>(cursor, Nn);
        hist_kernel<<<eb, 256, 0, stream>>>(ei[t] + Ee, cursor, Ee);
        scan_kernel<<<1, 1024, 0, stream>>>(cursor, row_off, Nn);
        scatter_kernel<<<eb, 256, 0, stream>>>(ei[t], ei[t] + Ee, cursor, ssrc, Ee);

        u16 *hA = Hhi, *hB = Hlo, *nA = Hnhi, *nB = Hnlo;
        for (int s = 0; s < 4; ++s) {
            hagg_k<<<ab, 256, 0, stream>>>(hA, hB, row_off, ssrc, AGhi, AGlo, Nn, Npad);
            gru3_k<<<gbg, 512, 0, stream>>>(AGhi, AGlo, hA, hB,
                                            WfHi[t] + (size_t)s * 49152, WfLo[t] + (size_t)s * 49152,
                                            WhHi[t], WhLo[t], bihp[t], bhhp[t], nA, nB);
            u16* tp;
            tp = hA; hA = nA; nA = tp;
            tp = hB; hB = nB; nB = tp;
        }
        pool_k<<<Gg, 256, 0, stream>>>(hA, hB, batch, pool2[t], Nn);
    }
    pred_kernel<<<Gg, 64, 0, stream>>>(pooledA, pooledV, pred_W, pred_b, out);
}

// Round 4
// 1751.315 us; speedup vs baseline: 2.1170x; 1.0667x over previous
//
#include <hip/hip_runtime.h>
#include <math.h>

#define HDIM 128
typedef unsigned short u16;
typedef __attribute__((ext_vector_type(8))) short bf16x8;
typedef __attribute__((ext_vector_type(4))) float f32x4;

__device__ __forceinline__ u16 f2bf(float x) {
    unsigned u = __float_as_uint(x);
    u = (u + 0x7FFFu + ((u >> 16) & 1u)) >> 16;
    return (u16)u;
}
__device__ __forceinline__ float bf2f(u16 h) {
    return __uint_as_float(((unsigned)h) << 16);
}
__device__ __forceinline__ bf16x8 ld8(const u16* p) {
    return *reinterpret_cast<const bf16x8*>(p);
}
#define MFMA(acc, a, b) acc = __builtin_amdgcn_mfma_f32_16x16x32_bf16(a, b, acc, 0, 0, 0)

// ---------------- weight prep -----------------------------------------------
// Wfull[s][c2][r] = dot(Ws[s][r][:], Wih[c2][:])  (gi = (hagg@Ws)@Wih^T), hi/lo
__global__ __launch_bounds__(256) void prep_wfull(const float* __restrict__ Ws,
                                                  const float* __restrict__ Wih,
                                                  u16* __restrict__ hi, u16* __restrict__ lo) {
    int s = blockIdx.y;
    int idx = blockIdx.x * 256 + threadIdx.x;   // [0, 49152)
    int c2 = idx >> 7, r = idx & 127;
    const float* wr = Ws + (size_t)s * 16384 + (size_t)r * 128;
    const float* wc = Wih + (size_t)c2 * 128;
    float acc = 0.f;
#pragma unroll 8
    for (int k = 0; k < 128; k += 4) {
        float4 a = *reinterpret_cast<const float4*>(wr + k);
        float4 b = *reinterpret_cast<const float4*>(wc + k);
        acc += a.x * b.x + a.y * b.y + a.z * b.z + a.w * b.w;
    }
    size_t o = (size_t)s * 49152 + idx;
    u16 h = f2bf(acc);
    hi[o] = h; lo[o] = f2bf(acc - bf2f(h));
}

// straight split (Whh is already B^T = [384][128] row-major)
__global__ __launch_bounds__(256) void prep_split(const float* __restrict__ W,
                                                  u16* __restrict__ hi, u16* __restrict__ lo, int n) {
    int i = blockIdx.x * 256 + threadIdx.x;
    if (i < n) { float v = W[i]; u16 h = f2bf(v); hi[i] = h; lo[i] = f2bf(v - bf2f(h)); }
}

// WinT[r][c] = W_in[c][r], [128][64]
__global__ __launch_bounds__(256) void prep_win(const float* __restrict__ W,
                                                u16* __restrict__ hi, u16* __restrict__ lo) {
    int idx = blockIdx.x * 256 + threadIdx.x;        // 0..8191
    int r = idx >> 6, c = idx & 63;
    float v = W[(size_t)c * 128 + r];
    u16 h = f2bf(v);
    hi[idx] = h; lo[idx] = f2bf(v - bf2f(h));
}

// split x -> padded bf16 hi/lo
__global__ __launch_bounds__(256) void split_x(const float* __restrict__ x,
                                               u16* __restrict__ hi, u16* __restrict__ lo,
                                               int n, int ntot) {
    int i = blockIdx.x * 256 + threadIdx.x;
    if (i >= ntot) return;
    float v = (i < n) ? x[i] : 0.f;
    u16 h = f2bf(v);
    hi[i] = h; lo[i] = f2bf(v - bf2f(h));
}

// ---------------- embed: H = tanh(X @ Win), K=64 ----------------------------
__global__ __launch_bounds__(256) void embed_k(const u16* __restrict__ Xhi, const u16* __restrict__ Xlo,
                                               const u16* __restrict__ Bhi, const u16* __restrict__ Blo,
                                               u16* __restrict__ Hhi, u16* __restrict__ Hlo) {
    const int tid = threadIdx.x, wave = tid >> 6, lane = tid & 63;
    const int row0 = blockIdx.x * 32, cs = wave * 32;
    const int lr = lane & 15, lk = (lane >> 4) * 8;
    f32x4 acc[2][2];
#pragma unroll
    for (int i = 0; i < 2; ++i)
#pragma unroll
        for (int j = 0; j < 2; ++j) acc[i][j] = (f32x4)0.f;
#pragma unroll
    for (int kc = 0; kc < 2; ++kc) {
        const size_t ao = (size_t)(row0 + lr) * 64 + kc * 32 + lk;
        bf16x8 ah0 = ld8(Xhi + ao), ah1 = ld8(Xhi + ao + 16 * 64);
        bf16x8 al0 = ld8(Xlo + ao), al1 = ld8(Xlo + ao + 16 * 64);
#pragma unroll
        for (int cf = 0; cf < 2; ++cf) {
            const size_t bo = (size_t)(cs + cf * 16 + lr) * 64 + kc * 32 + lk;
            bf16x8 bh = ld8(Bhi + bo), bl = ld8(Blo + bo);
            MFMA(acc[0][cf], ah0, bh); MFMA(acc[0][cf], ah0, bl); MFMA(acc[0][cf], al0, bh);
            MFMA(acc[1][cf], ah1, bh); MFMA(acc[1][cf], ah1, bl); MFMA(acc[1][cf], al1, bh);
        }
    }
#pragma unroll
    for (int rf = 0; rf < 2; ++rf)
#pragma unroll
        for (int cf = 0; cf < 2; ++cf)
#pragma unroll
            for (int rg = 0; rg < 4; ++rg) {
                int row = row0 + rf * 16 + (lane >> 4) * 4 + rg;
                int col = cs + cf * 16 + lr;
                float v = tanhf(acc[rf][cf][rg]);
                u16 h = f2bf(v);
                size_t o = (size_t)row * HDIM + col;
                Hhi[o] = h; Hlo[o] = f2bf(v - bf2f(h));
            }
}

// ---------------- fused step: gather(h) -> LDS, then GRU GEMM + gates -------
// 512 threads = 8 waves; block covers 32 node-rows.
// phase 1: wave w gathers nodes w*4..w*4+3 (full 128 cols, 2 per lane).
// phase 2: wave w computes cols w*16..w*16+16 of all 6 gate strips.
__global__ __launch_bounds__(512, 4) void step_k(const u16* __restrict__ Hhi, const u16* __restrict__ Hlo,
                                                 const int* __restrict__ row_off, const int* __restrict__ ssrc,
                                                 const u16* __restrict__ Wfhi, const u16* __restrict__ Wflo,
                                                 const u16* __restrict__ Whhi, const u16* __restrict__ Whlo,
                                                 const float* __restrict__ bih, const float* __restrict__ bhh,
                                                 u16* __restrict__ Hnhi, u16* __restrict__ Hnlo, int Nn) {
    __shared__ u16 agh[32][136];   // stride 272B: 16B-aligned rows, minimal bank aliasing
    __shared__ u16 agl[32][136];
    const int tid = threadIdx.x, wave = tid >> 6, lane = tid & 63;
    const int row0 = blockIdx.x * 32;

    // ---- phase 1: gather neighbor-sum of h ----
#pragma unroll
    for (int q = 0; q < 4; ++q) {
        const int nl = wave * 4 + q;
        const int node = row0 + nl;
        float ax = 0.f, ay = 0.f;
        if (node < Nn) {
            int lo = row_off[node], hi = row_off[node + 1];
            int i = lo;
            for (; i + 3 < hi; i += 4) {
                int s0 = ssrc[i], s1 = ssrc[i + 1], s2 = ssrc[i + 2], s3 = ssrc[i + 3];
                unsigned h0 = *reinterpret_cast<const unsigned*>(Hhi + (size_t)s0 * HDIM + lane * 2);
                unsigned l0 = *reinterpret_cast<const unsigned*>(Hlo + (size_t)s0 * HDIM + lane * 2);
                unsigned h1 = *reinterpret_cast<const unsigned*>(Hhi + (size_t)s1 * HDIM + lane * 2);
                unsigned l1 = *reinterpret_cast<const unsigned*>(Hlo + (size_t)s1 * HDIM + lane * 2);
                unsigned h2 = *reinterpret_cast<const unsigned*>(Hhi + (size_t)s2 * HDIM + lane * 2);
                unsigned l2 = *reinterpret_cast<const unsigned*>(Hlo + (size_t)s2 * HDIM + lane * 2);
                unsigned h3 = *reinterpret_cast<const unsigned*>(Hhi + (size_t)s3 * HDIM + lane * 2);
                unsigned l3 = *reinterpret_cast<const unsigned*>(Hlo + (size_t)s3 * HDIM + lane * 2);
                ax += bf2f((u16)h0) + bf2f((u16)l0) + bf2f((u16)h1) + bf2f((u16)l1)
                    + bf2f((u16)h2) + bf2f((u16)l2) + bf2f((u16)h3) + bf2f((u16)l3);
                ay += bf2f((u16)(h0 >> 16)) + bf2f((u16)(l0 >> 16)) + bf2f((u16)(h1 >> 16)) + bf2f((u16)(l1 >> 16))
                    + bf2f((u16)(h2 >> 16)) + bf2f((u16)(l2 >> 16)) + bf2f((u16)(h3 >> 16)) + bf2f((u16)(l3 >> 16));
            }
            for (; i < hi; ++i) {
                int s = ssrc[i];
                unsigned h = *reinterpret_cast<const unsigned*>(Hhi + (size_t)s * HDIM + lane * 2);
                unsigned l = *reinterpret_cast<const unsigned*>(Hlo + (size_t)s * HDIM + lane * 2);
                ax += bf2f((u16)h) + bf2f((u16)l);
                ay += bf2f((u16)(h >> 16)) + bf2f((u16)(l >> 16));
            }
        }
        u16 hx = f2bf(ax), hy = f2bf(ay);
        u16 lx = f2bf(ax - bf2f(hx)), ly = f2bf(ay - bf2f(hy));
        *reinterpret_cast<unsigned*>(&agh[nl][lane * 2]) = (unsigned)hx | ((unsigned)hy << 16);
        *reinterpret_cast<unsigned*>(&agl[nl][lane * 2]) = (unsigned)lx | ((unsigned)ly << 16);
    }
    __syncthreads();

    // ---- phase 2: GEMM + gates ----
    const int lr = lane & 15, lk = (lane >> 4) * 8, cs = wave * 16;
    f32x4 accI[2][3], accH[2][3];
#pragma unroll
    for (int rf = 0; rf < 2; ++rf)
#pragma unroll
        for (int g = 0; g < 3; ++g) { accI[rf][g] = (f32x4)0.f; accH[rf][g] = (f32x4)0.f; }
#pragma unroll
    for (int kc = 0; kc < 4; ++kc) {
        bf16x8 ga[2], gl[2], ha[2], hl[2];
#pragma unroll
        for (int rf = 0; rf < 2; ++rf) {
            ga[rf] = *reinterpret_cast<const bf16x8*>(&agh[rf * 16 + lr][kc * 32 + lk]);
            gl[rf] = *reinterpret_cast<const bf16x8*>(&agl[rf * 16 + lr][kc * 32 + lk]);
            const size_t ao = (size_t)(row0 + rf * 16 + lr) * HDIM + kc * 32 + lk;
            ha[rf] = ld8(Hhi + ao); hl[rf] = ld8(Hlo + ao);
        }
#pragma unroll
        for (int g = 0; g < 3; ++g) {
            const size_t bo = (size_t)(g * 128 + cs + lr) * HDIM + kc * 32 + lk;
            bf16x8 fh = ld8(Wfhi + bo), fl = ld8(Wflo + bo);
            bf16x8 wh = ld8(Whhi + bo), wl = ld8(Whlo + bo);
#pragma unroll
            for (int rf = 0; rf < 2; ++rf) {
                MFMA(accI[rf][g], ga[rf], fh); MFMA(accI[rf][g], ga[rf], fl); MFMA(accI[rf][g], gl[rf], fh);
                MFMA(accH[rf][g], ha[rf], wh); MFMA(accH[rf][g], ha[rf], wl); MFMA(accH[rf][g], hl[rf], wh);
            }
        }
    }
    const int c = cs + lr;
    const float bir = bih[c], biz = bih[128 + c], bin = bih[256 + c];
    const float bhr = bhh[c], bhz = bhh[128 + c], bhn = bhh[256 + c];
#pragma unroll
    for (int rf = 0; rf < 2; ++rf)
#pragma unroll
        for (int rg = 0; rg < 4; ++rg) {
            const int row = row0 + rf * 16 + (lane >> 4) * 4 + rg;
            float gir = accI[rf][0][rg] + bir;
            float giz = accI[rf][1][rg] + biz;
            float gin = accI[rf][2][rg] + bin;
            float ghr = accH[rf][0][rg] + bhr;
            float ghz = accH[rf][1][rg] + bhz;
            float ghn = accH[rf][2][rg] + bhn;
            float r = 1.f / (1.f + expf(-(gir + ghr)));
            float z = 1.f / (1.f + expf(-(giz + ghz)));
            float nn = tanhf(gin + r * ghn);
            size_t o = (size_t)row * HDIM + c;
            float hold = bf2f(Hhi[o]) + bf2f(Hlo[o]);
            float hn = (1.f - z) * nn + z * hold;
            u16 hh = f2bf(hn);
            Hnhi[o] = hh; Hnlo[o] = f2bf(hn - bf2f(hh));
        }
}

// ---------------- CSR build -------------------------------------------------
__global__ void zero_int(int* p, int n) {
    int i = blockIdx.x * 256 + threadIdx.x;
    if (i < n) p[i] = 0;
}

__global__ void hist_kernel(const int* __restrict__ dst, int* __restrict__ cnt, int E) {
    int e = blockIdx.x * 256 + threadIdx.x;
    if (e < E) atomicAdd(&cnt[dst[e]], 1);
}

// single-block chunked exclusive scan with wave shuffles
__global__ __launch_bounds__(1024) void scan_kernel(int* __restrict__ cnt_cursor,
                                                    int* __restrict__ row_off, int n) {
    __shared__ int wsum[16];
    __shared__ int carry_s;
    const int tid = threadIdx.x, lane = tid & 63, wv = tid >> 6;
    if (tid == 0) carry_s = 0;
    __syncthreads();
    for (int base = 0; base < n; base += 1024) {
        int i = base + tid;
        int v = (i < n) ? cnt_cursor[i] : 0;
        int x = v;
#pragma unroll
        for (int off = 1; off < 64; off <<= 1) {
            int t = __shfl_up(x, off);
            if (lane >= off) x += t;
        }
        if (lane == 63) wsum[wv] = x;
        __syncthreads();
        if (wv == 0 && lane < 16) {
            int s = wsum[lane];
#pragma unroll
            for (int off = 1; off < 16; off <<= 1) {
                int t = __shfl_up(s, off);
                if (lane >= off) s += t;
            }
            wsum[lane] = s;
        }
        __syncthreads();
        int wbase = (wv == 0) ? 0 : wsum[wv - 1];
        int carry = carry_s;
        int total = wsum[15];
        int excl = carry + wbase + x - v;
        if (i < n) { row_off[i] = excl; cnt_cursor[i] = excl; }
        __syncthreads();
        if (tid == 0) carry_s = carry + total;
        __syncthreads();
    }
    if (tid == 0) row_off[n] = carry_s;
}

__global__ void scatter_kernel(const int* __restrict__ src, const int* __restrict__ dst,
                               int* __restrict__ cursor, int* __restrict__ ssrc, int E) {
    int e = blockIdx.x * 256 + threadIdx.x;
    if (e < E) {
        int p = atomicAdd(&cursor[dst[e]], 1);
        ssrc[p] = src[e];
    }
}

// ---------------- mean-pool + relu ------------------------------------------
__global__ __launch_bounds__(256) void pool_k(const u16* __restrict__ Hhi, const u16* __restrict__ Hlo,
                                              const int* __restrict__ batch,
                                              float* __restrict__ pooled, int M) {
    __shared__ int lo_s, hi_s;
    __shared__ float smx[256], smy[256];
    int g = blockIdx.x;
    if (threadIdx.x == 0) {
        int lo = 0, hi = M;
        while (lo < hi) { int mid = (lo + hi) >> 1; if (batch[mid] < g) lo = mid + 1; else hi = mid; }
        lo_s = lo;
        int lo2 = lo, hi2 = M;
        while (lo2 < hi2) { int mid = (lo2 + hi2) >> 1; if (batch[mid] < g + 1) lo2 = mid + 1; else hi2 = mid; }
        hi_s = lo2;
    }
    __syncthreads();
    int lo = lo_s, hi = hi_s;
    int c2 = threadIdx.x & 63, quarter = threadIdx.x >> 6;
    float ax = 0.f, ay = 0.f;
    for (int i = lo + quarter; i < hi; i += 4) {
        unsigned uh = *reinterpret_cast<const unsigned*>(Hhi + (size_t)i * HDIM + c2 * 2);
        unsigned ul = *reinterpret_cast<const unsigned*>(Hlo + (size_t)i * HDIM + c2 * 2);
        ax += bf2f((u16)(uh & 0xFFFF)) + bf2f((u16)(ul & 0xFFFF));
        ay += bf2f((u16)(uh >> 16)) + bf2f((u16)(ul >> 16));
    }
    smx[threadIdx.x] = ax; smy[threadIdx.x] = ay;
    __syncthreads();
    if (quarter == 0) {
        float sx = smx[c2] + smx[c2 + 64] + smx[c2 + 128] + smx[c2 + 192];
        float sy = smy[c2] + smy[c2 + 64] + smy[c2 + 128] + smy[c2 + 192];
        float cnt = (float)(hi - lo); if (cnt < 1.f) cnt = 1.f;
        pooled[g * HDIM + c2 * 2]     = fmaxf(sx / cnt, 0.f);
        pooled[g * HDIM + c2 * 2 + 1] = fmaxf(sy / cnt, 0.f);
    }
}

// ---------------- prediction head -------------------------------------------
__global__ void pred_kernel(const float* __restrict__ pa, const float* __restrict__ pv,
                            const float* __restrict__ pW, const float* __restrict__ pb,
                            float* __restrict__ out) {
    int g = blockIdx.x, lane = threadIdx.x; // 64 threads
    float s = pa[g * HDIM + lane] * pW[lane]
            + pa[g * HDIM + 64 + lane] * pW[64 + lane]
            + pv[g * HDIM + lane] * pW[HDIM + lane]
            + pv[g * HDIM + 64 + lane] * pW[192 + lane];
    for (int off = 32; off; off >>= 1) s += __shfl_down(s, off);
    if (lane == 0) out[g] = s + pb[0];
}

extern "C" void kernel_launch(void* const* d_in, const int* in_sizes, int n_in,
                              void* d_out, int out_size, void* d_ws, size_t ws_size,
                              hipStream_t stream) {
    const float* atom_x   = (const float*)d_in[0];
    const float* voro_x   = (const float*)d_in[1];
    const int*   atom_ei  = (const int*)d_in[2];
    const int*   voro_ei  = (const int*)d_in[3];
    const int*   batch    = (const int*)d_in[4];
    const float* W_at_in  = (const float*)d_in[5];
    const float* W_vo_in  = (const float*)d_in[6];
    const float* atom_W   = (const float*)d_in[7];
    const float* voro_W   = (const float*)d_in[8];
    const float* atom_Wih = (const float*)d_in[9];
    const float* atom_Whh = (const float*)d_in[10];
    const float* atom_bih = (const float*)d_in[11];
    const float* atom_bhh = (const float*)d_in[12];
    const float* voro_Wih = (const float*)d_in[13];
    const float* voro_Whh = (const float*)d_in[14];
    const float* voro_bih = (const float*)d_in[15];
    const float* voro_bhh = (const float*)d_in[16];
    const float* pred_W   = (const float*)d_in[17];
    const float* pred_b   = (const float*)d_in[18];
    float* out = (float*)d_out;

    const int Nn = in_sizes[4];
    const int Ee = in_sizes[2] / 2;
    const int Gg = out_size;
    const int Npad = (Nn + 63) & ~63;

    char* base = (char*)d_ws;
    size_t off = 0;
    auto alloc = [&](size_t bytes) -> char* {
        char* p = base + off;
        off = (off + bytes + 255) & ~(size_t)255;
        return p;
    };

    u16* Hhi  = (u16*)alloc((size_t)Npad * HDIM * 2);
    u16* Hlo  = (u16*)alloc((size_t)Npad * HDIM * 2);
    u16* Hnhi = (u16*)alloc((size_t)Npad * HDIM * 2);
    u16* Hnlo = (u16*)alloc((size_t)Npad * HDIM * 2);
    u16* Xhi  = (u16*)alloc((size_t)Npad * 64 * 2);
    u16* Xlo  = (u16*)alloc((size_t)Npad * 64 * 2);
    u16 *WfHi[2], *WfLo[2], *WhHi[2], *WhLo[2], *WnHi[2], *WnLo[2];
    for (int t = 0; t < 2; ++t) {
        WfHi[t] = (u16*)alloc(4 * 49152 * 2); WfLo[t] = (u16*)alloc(4 * 49152 * 2);
        WhHi[t] = (u16*)alloc(384 * 128 * 2); WhLo[t] = (u16*)alloc(384 * 128 * 2);
        WnHi[t] = (u16*)alloc(128 * 64 * 2);  WnLo[t] = (u16*)alloc(128 * 64 * 2);
    }
    float* pooledA = (float*)alloc((size_t)Gg * HDIM * 4);
    float* pooledV = (float*)alloc((size_t)Gg * HDIM * 4);
    int* row_off = (int*)alloc((size_t)(Nn + 1) * 4);
    int* cursor  = (int*)alloc((size_t)Nn * 4);
    int* ssrc    = (int*)alloc((size_t)Ee * 4);

    const float* xs[2]   = {atom_x, voro_x};
    const float* Win[2]  = {W_at_in, W_vo_in};
    const int*   ei[2]   = {atom_ei, voro_ei};
    const float* Wst[2]  = {atom_W, voro_W};
    const float* Wih[2]  = {atom_Wih, voro_Wih};
    const float* Whh[2]  = {atom_Whh, voro_Whh};
    const float* bihp[2] = {atom_bih, voro_bih};
    const float* bhhp[2] = {atom_bhh, voro_bhh};
    float* pool2[2]      = {pooledA, pooledV};

    // weight prep
    for (int t = 0; t < 2; ++t) {
        prep_wfull<<<dim3(192, 4), 256, 0, stream>>>(Wst[t], Wih[t], WfHi[t], WfLo[t]);
        prep_split<<<192, 256, 0, stream>>>(Whh[t], WhHi[t], WhLo[t], 384 * 128);
        prep_win<<<32, 256, 0, stream>>>(Win[t], WnHi[t], WnLo[t]);
    }

    const int eb = (Ee + 255) / 256;
    const int nb = (Nn + 255) / 256;
    const int gbe = Npad / 32;
    const int gbs = Npad / 32;

    for (int t = 0; t < 2; ++t) {
        split_x<<<(Npad * 64 + 255) / 256, 256, 0, stream>>>(xs[t], Xhi, Xlo, Nn * 64, Npad * 64);
        embed_k<<<gbe, 256, 0, stream>>>(Xhi, Xlo, WnHi[t], WnLo[t], Hhi, Hlo);

        zero_int<<<nb, 256, 0, stream>>>(cursor, Nn);
        hist_kernel<<<eb, 256, 0, stream>>>(ei[t] + Ee, cursor, Ee);
        scan_kernel<<<1, 1024, 0, stream>>>(cursor, row_off, Nn);
        scatter_kernel<<<eb, 256, 0, stream>>>(ei[t], ei[t] + Ee, cursor, ssrc, Ee);

        u16 *hA = Hhi, *hB = Hlo, *nA = Hnhi, *nB = Hnlo;
        for (int s = 0; s < 4; ++s) {
            step_k<<<gbs, 512, 0, stream>>>(hA, hB, row_off, ssrc,
                                            WfHi[t] + (size_t)s * 49152, WfLo[t] + (size_t)s * 49152,
                                            WhHi[t], WhLo[t], bihp[t], bhhp[t], nA, nB, Nn);
            u16* tp;
            tp = hA; hA = nA; nA = tp;
            tp = hB; hB = nB; nB = tp;
        }
        pool_k<<<Gg, 256, 0, stream>>>(hA, hB, batch, pool2[t], Nn);
    }
    pred_kernel<<<Gg, 64, 0, stream>>>(pooledA, pooledV, pred_W, pred_b, out);
}